// Round 7
// baseline (685.921 us; speedup 1.0000x reference)
//
#include <hip/hip_runtime.h>
#include <cstdint>
#include <cstddef>

#define S_ 2048
#define D_ 64
#define KSL 256          // k-slice per wave
#define PSTR 272         // stash row stride (bf16 elems): 544 B, 8 banks offset/row

typedef __attribute__((ext_vector_type(4))) float f32x4;
typedef __attribute__((ext_vector_type(4))) int i32x4;
typedef __attribute__((ext_vector_type(8))) __bf16 bf16x8;
typedef __attribute__((ext_vector_type(8))) unsigned short us8;
typedef __attribute__((ext_vector_type(4))) unsigned short us4;

static __device__ __forceinline__ unsigned short f2bf(float f) {
  unsigned int u = __builtin_bit_cast(unsigned int, f);
  u += 0x7fffu + ((u >> 16) & 1u);          // RNE (no NaNs in this problem)
  return (unsigned short)(u >> 16);
}
static __device__ __forceinline__ float bf2f(unsigned short h) {
  unsigned int u = ((unsigned int)h) << 16;
  return __builtin_bit_cast(float, u);
}
static __device__ __forceinline__ bf16x8 cvt8(const float* p) {
  f32x4 a = *(const f32x4*)p;
  f32x4 b = *(const f32x4*)(p + 4);
  us8 t;
  t[0]=f2bf(a[0]); t[1]=f2bf(a[1]); t[2]=f2bf(a[2]); t[3]=f2bf(a[3]);
  t[4]=f2bf(b[0]); t[5]=f2bf(b[1]); t[6]=f2bf(b[2]); t[7]=f2bf(b[3]);
  return __builtin_bit_cast(bf16x8, t);
}

// ---------- prekernel 1: f32 -> bf16 elementwise (Q, K) ----------
__global__ __launch_bounds__(256)
void cvt_bf16_kernel(const float* __restrict__ src, unsigned short* __restrict__ dst, int n4) {
  int i = blockIdx.x * 256 + threadIdx.x;
  int stride = gridDim.x * 256;
  for (; i < n4; i += stride) {
    f32x4 v = ((const f32x4*)src)[i];
    us4 o; o[0]=f2bf(v[0]); o[1]=f2bf(v[1]); o[2]=f2bf(v[2]); o[3]=f2bf(v[3]);
    ((us4*)dst)[i] = o;
  }
}

// ---------- prekernel 2: V [bh][s][d] f32 -> Vt [bh][d][s] bf16 ----------
__global__ __launch_bounds__(256)
void vtrans_kernel(const float* __restrict__ V, unsigned short* __restrict__ Vt) {
  __shared__ unsigned short T[64][72];
  const int bh = blockIdx.x >> 5;
  const int s0 = (blockIdx.x & 31) * 64;
  const int tid = threadIdx.x;
#pragma unroll
  for (int it = 0; it < 4; ++it) {
    int idx = it * 256 + tid;
    int s = idx >> 4, d4 = (idx & 15) * 4;
    f32x4 v = *(const f32x4*)&V[((size_t)bh * S_ + s0 + s) * D_ + d4];
    T[s][d4+0] = f2bf(v[0]); T[s][d4+1] = f2bf(v[1]);
    T[s][d4+2] = f2bf(v[2]); T[s][d4+3] = f2bf(v[3]);
  }
  __syncthreads();
#pragma unroll
  for (int it = 0; it < 2; ++it) {
    int idx = it * 256 + tid;
    int d = idx >> 3, s8 = (idx & 7) * 8;
    us8 w;
#pragma unroll
    for (int j = 0; j < 8; ++j) w[j] = T[s8 + j][d];
    *(us8*)&Vt[((size_t)bh * D_ + d) * S_ + s0 + s8] = w;
  }
}

// ---------- main fused attention: single QK^T pass, stash exp in LDS,
// store-only pass 2 (PV from stash, normalize deferred to epilogue) ----------
template<int PRE>
__global__ __launch_bounds__(512, 4)
void attn_kernel(const float* __restrict__ Q, const float* __restrict__ K,
                 const float* __restrict__ V, const int* __restrict__ M,
                 const unsigned short* __restrict__ Qb,
                 const unsigned short* __restrict__ Kb,
                 const unsigned short* __restrict__ Vt,
                 float* __restrict__ outO, float* __restrict__ outP)
{
  // wave-private un-normalized exp stash [wave][16 q][256 k (+pad)] bf16 (69.6 KB)
  __shared__ __align__(16) unsigned short sP[8][16][PSTR];
  __shared__ float sRed[8][16];
  __shared__ float sSum[16];

  const int tid  = threadIdx.x;
  const int wid  = tid >> 6;      // 0..7, owns k-slice [wid*256, wid*256+256)
  const int lane = tid & 63;
  const int l15  = lane & 15;
  const int l4   = lane >> 4;
  const int kbase = wid * KSL;

  // XCD swizzle: 8192 blocks = 8 * 1024 (bijective); heads grouped per XCD.
  const int bid = ((blockIdx.x & 7) << 10) | (blockIdx.x >> 3);
  const int bh = bid >> 7;     // 0..63
  const int qt = bid & 127;    // 16-row Q tile
  const int b  = bh >> 4;

  const float* Qh = Q + ((size_t)bh * S_ + (size_t)qt * 16) * D_;
  const float* Kh = K + (size_t)bh * S_ * D_;
  const float* Vh = V + (size_t)bh * S_ * D_;
  const int*   Mb = M + (size_t)b * S_;
  float* Ph = outP + (size_t)bh * S_ * S_ + (size_t)qt * 16 * S_;
  float* Oh = outO + ((size_t)bh * S_ + (size_t)qt * 16) * D_;

  // Q fragments (B-operand of swapped QK^T): lane = q-row l15, depth l4*8
  bf16x8 qa[2];
#pragma unroll
  for (int sk = 0; sk < 2; ++sk) {
    if (PRE)
      qa[sk] = __builtin_bit_cast(bf16x8,
        *(const us8*)&Qb[((size_t)(bh * S_ + qt*16 + l15)) * D_ + sk*32 + l4*8]);
    else
      qa[sk] = cvt8(Qh + l15 * D_ + sk*32 + l4*8);
  }

  // ---------- pass 1: QK^T (swapped) + exp -> stash + row sums. NO stores. ----------
  float rs = 0.f;
  for (int i = 0; i < KSL/16; ++i) {
    const int col0 = kbase + i*16;
    const i32x4 mk4 = *(const i32x4*)&Mb[col0 + l4*4];
    bf16x8 kf0, kf1;
    if (PRE) {
      const unsigned short* kp = &Kb[(size_t)(bh * S_ + col0 + l15) * D_ + l4*8];
      kf0 = __builtin_bit_cast(bf16x8, *(const us8*)kp);
      kf1 = __builtin_bit_cast(bf16x8, *(const us8*)(kp + 32));
    } else {
      const float* kp = Kh + (size_t)(col0 + l15) * D_ + l4*8;
      kf0 = cvt8(kp); kf1 = cvt8(kp + 32);
    }
    f32x4 acc = {0.f,0.f,0.f,0.f};
    acc = __builtin_amdgcn_mfma_f32_16x16x32_bf16(kf0, qa[0], acc, 0,0,0);
    acc = __builtin_amdgcn_mfma_f32_16x16x32_bf16(kf1, qa[1], acc, 0,0,0);
    // lane holds S[k=col0+l4*4+r][q=l15]
    us4 pb;
#pragma unroll
    for (int r = 0; r < 4; ++r) {
      float e = mk4[r] ? __expf(acc[r] * 0.125f) : 0.f;
      rs += e;
      pb[r] = f2bf(e);
    }
    *(us4*)&sP[wid][l15][i*16 + l4*4] = pb;   // 8B ds_write, un-normalized exp
  }
  rs += __shfl_xor(rs, 16);
  rs += __shfl_xor(rs, 32);
  if (lane < 16) sRed[wid][l15] = rs;
  __syncthreads();
  if (tid < 16) {
    float t = 0.f;
#pragma unroll
    for (int w = 0; w < 8; ++w) t += sRed[w][tid];
    sSum[tid] = 1.0f / t;
  }
  __syncthreads();
  const float rvq = sSum[l15];

  // ---------- pass 2: STORE-ONLY VMEM (except prefetched V). PV from stash. ----------
  f32x4 oacc[4];
#pragma unroll
  for (int dt = 0; dt < 4; ++dt) oacc[dt] = (f32x4){0.f,0.f,0.f,0.f};

  const unsigned short* VtW = PRE ? &Vt[(size_t)bh * D_ * S_] : nullptr;

  us8 vb[4];
#pragma unroll
  for (int dt = 0; dt < 4; ++dt) {
    if (PRE) {
      vb[dt] = *(const us8*)&VtW[(size_t)(dt*16 + l15) * S_ + kbase + l4*8];
    } else {
#pragma unroll
      for (int j = 0; j < 8; ++j)
        vb[dt][j] = f2bf(Vh[(size_t)(kbase + l4*8 + j) * D_ + dt*16 + l15]);
    }
  }

  for (int step = 0; step < KSL/32; ++step) {
    const int kloc = step * 32;
    // prefetch next step's V
    us8 vn[4];
    if (step < KSL/32 - 1) {
#pragma unroll
      for (int dt = 0; dt < 4; ++dt) {
        if (PRE) {
          vn[dt] = *(const us8*)&VtW[(size_t)(dt*16 + l15) * S_ + kbase + kloc + 32 + l4*8];
        } else {
#pragma unroll
          for (int j = 0; j < 8; ++j)
            vn[dt][j] = f2bf(Vh[(size_t)(kbase + kloc + 32 + l4*8 + j) * D_ + dt*16 + l15]);
        }
      }
    }
    // stash read = PV A-fragment AND P-store source (8 k of q=l15)
    us8 pa = *(const us8*)&sP[wid][l15][kloc + l4*8];
    // P store: p = exp_bf16 * rv  (16B/lane x2; rows fully covered -> L2 write-combine)
    f32x4 w0, w1;
#pragma unroll
    for (int j = 0; j < 4; ++j) { w0[j] = bf2f(pa[j]) * rvq; w1[j] = bf2f(pa[4+j]) * rvq; }
    float* pp = &Ph[(size_t)l15 * S_ + kbase + kloc + l4*8];
    *(f32x4*)pp = w0;
    *(f32x4*)(pp + 4) = w1;
    // PV MFMA with un-normalized P (normalization deferred to epilogue)
#pragma unroll
    for (int dt = 0; dt < 4; ++dt)
      oacc[dt] = __builtin_amdgcn_mfma_f32_16x16x32_bf16(
                     __builtin_bit_cast(bf16x8, pa),
                     __builtin_bit_cast(bf16x8, vb[dt]), oacc[dt], 0,0,0);
    if (step < KSL/32 - 1) {
#pragma unroll
      for (int dt = 0; dt < 4; ++dt) vb[dt] = vn[dt];
    }
  }

  // ---------- epilogue: cross-wave O reduction + deferred normalization ----------
  float* sO = (float*)&sP[0][0][0];   // [8][16][64] f32 (32 KB) aliases sP
  __syncthreads();                    // all stash reads complete
#pragma unroll
  for (int dt = 0; dt < 4; ++dt)
#pragma unroll
    for (int r = 0; r < 4; ++r)
      sO[wid*1024 + (l4*4 + r)*64 + dt*16 + l15] = oacc[dt][r];
  __syncthreads();
  if (tid < 256) {
    const int row = tid >> 4;
    const int d0 = (tid & 15) * 4;
    f32x4 s = {0.f,0.f,0.f,0.f};
#pragma unroll
    for (int w = 0; w < 8; ++w)
      s += *(const f32x4*)&sO[w*1024 + row*64 + d0];
    const float rv = sSum[row];
    s[0]*=rv; s[1]*=rv; s[2]*=rv; s[3]*=rv;
    *(f32x4*)&Oh[(size_t)row * D_ + d0] = s;
  }
}

extern "C" void kernel_launch(void* const* d_in, const int* in_sizes, int n_in,
                              void* d_out, int out_size, void* d_ws, size_t ws_size,
                              hipStream_t stream) {
  const float* Q = (const float*)d_in[0];
  const float* K = (const float*)d_in[1];
  const float* V = (const float*)d_in[2];
  const int*   M = (const int*)d_in[3];
  float* outO = (float*)d_out;                                  // (B,H,S,D)
  float* outP = (float*)d_out + (size_t)4 * 16 * 2048 * 64;     // (B,H,S,S)

  const size_t bytesEach = (size_t)64 * 2048 * 64 * 2;          // 16 MiB per bf16 array
  const size_t need = 3 * bytesEach;

  if (ws_size >= need) {
    unsigned short* Vt = (unsigned short*)d_ws;
    unsigned short* Kb = (unsigned short*)((char*)d_ws + bytesEach);
    unsigned short* Qb = (unsigned short*)((char*)d_ws + 2 * bytesEach);
    const int n4 = 64 * 2048 * 64 / 4;
    cvt_bf16_kernel<<<dim3(2048), dim3(256), 0, stream>>>(K, Kb, n4);
    cvt_bf16_kernel<<<dim3(2048), dim3(256), 0, stream>>>(Q, Qb, n4);
    vtrans_kernel<<<dim3(2048), dim3(256), 0, stream>>>(V, Vt);
    attn_kernel<1><<<dim3(8192), dim3(512), 0, stream>>>(Q, K, V, M, Qb, Kb, Vt, outO, outP);
  } else {
    attn_kernel<0><<<dim3(8192), dim3(512), 0, stream>>>(Q, K, V, M,
        (const unsigned short*)nullptr, (const unsigned short*)nullptr,
        (const unsigned short*)nullptr, outO, outP);
  }
}

// Round 8
// 603.924 us; speedup vs baseline: 1.1358x; 1.1358x over previous
//
#include <hip/hip_runtime.h>
#include <cstdint>
#include <cstddef>

#define S_ 2048
#define D_ 64

typedef __attribute__((ext_vector_type(4))) float f32x4;
typedef __attribute__((ext_vector_type(4))) int i32x4;
typedef __attribute__((ext_vector_type(8))) __bf16 bf16x8;
typedef __attribute__((ext_vector_type(8))) unsigned short us8;
typedef __attribute__((ext_vector_type(4))) unsigned short us4;

static __device__ __forceinline__ unsigned short f2bf(float f) {
  unsigned int u = __builtin_bit_cast(unsigned int, f);
  u += 0x7fffu + ((u >> 16) & 1u);          // RNE (no NaNs in this problem)
  return (unsigned short)(u >> 16);
}
static __device__ __forceinline__ float bf2f(unsigned short h) {
  unsigned int u = ((unsigned int)h) << 16;
  return __builtin_bit_cast(float, u);
}
static __device__ __forceinline__ bf16x8 cvt8(const float* p) {
  f32x4 a = *(const f32x4*)p;
  f32x4 b = *(const f32x4*)(p + 4);
  us8 t;
  t[0]=f2bf(a[0]); t[1]=f2bf(a[1]); t[2]=f2bf(a[2]); t[3]=f2bf(a[3]);
  t[4]=f2bf(b[0]); t[5]=f2bf(b[1]); t[6]=f2bf(b[2]); t[7]=f2bf(b[3]);
  return __builtin_bit_cast(bf16x8, t);
}

// ---------- prekernel 1: f32 -> bf16 elementwise (Q, K) ----------
__global__ __launch_bounds__(256)
void cvt_bf16_kernel(const float* __restrict__ src, unsigned short* __restrict__ dst, int n4) {
  int i = blockIdx.x * 256 + threadIdx.x;
  int stride = gridDim.x * 256;
  for (; i < n4; i += stride) {
    f32x4 v = ((const f32x4*)src)[i];
    us4 o; o[0]=f2bf(v[0]); o[1]=f2bf(v[1]); o[2]=f2bf(v[2]); o[3]=f2bf(v[3]);
    ((us4*)dst)[i] = o;
  }
}

// ---------- prekernel 2: V [bh][s][d] f32 -> Vt [bh][d][s] bf16 ----------
__global__ __launch_bounds__(256)
void vtrans_kernel(const float* __restrict__ V, unsigned short* __restrict__ Vt) {
  __shared__ unsigned short T[64][72];
  const int bh = blockIdx.x >> 5;
  const int s0 = (blockIdx.x & 31) * 64;
  const int tid = threadIdx.x;
#pragma unroll
  for (int it = 0; it < 4; ++it) {
    int idx = it * 256 + tid;
    int s = idx >> 4, d4 = (idx & 15) * 4;
    f32x4 v = *(const f32x4*)&V[((size_t)bh * S_ + s0 + s) * D_ + d4];
    T[s][d4+0] = f2bf(v[0]); T[s][d4+1] = f2bf(v[1]);
    T[s][d4+2] = f2bf(v[2]); T[s][d4+3] = f2bf(v[3]);
  }
  __syncthreads();
#pragma unroll
  for (int it = 0; it < 2; ++it) {
    int idx = it * 256 + tid;
    int d = idx >> 3, s8 = (idx & 7) * 8;
    us8 w;
#pragma unroll
    for (int j = 0; j < 8; ++j) w[j] = T[s8 + j][d];
    *(us8*)&Vt[((size_t)bh * D_ + d) * S_ + s0 + s8] = w;
  }
}

// ---------- main fused attention: producer/consumer wave specialization ----------
// Waves 0-3: compute (loads only). Waves 4-7: P stores only (no loads, no vmcnt waits).
template<int PRE>
__global__ __launch_bounds__(512, 4)
void attn_kernel(const float* __restrict__ Q, const float* __restrict__ K,
                 const float* __restrict__ V, const int* __restrict__ M,
                 const unsigned short* __restrict__ Qb,
                 const unsigned short* __restrict__ Kb,
                 const unsigned short* __restrict__ Vt,
                 float* __restrict__ outO, float* __restrict__ outP)
{
  // per compute-wave double-buffered exp stash [cw][buf][32 q][64 k + pad] bf16 (40 KB);
  // compute wave cw's region aliased as f32 O-partial [32][64] in the epilogue.
  __shared__ __align__(16) unsigned short sP[4][2][32][80];
  __shared__ float sRed[4][32];
  __shared__ float sSum[32];
  __shared__ int sFlag[8];   // [0..3] = ready count (producer), [4..7] = done count (consumer)

  const int tid  = threadIdx.x;
  const int wid  = tid >> 6;      // 0..7
  const int lane = tid & 63;
  const int l15  = lane & 15;
  const int l4   = lane >> 4;
  const int cw   = wid & 3;       // compute-wave id / store wave's partner
  const int kbase = cw * 512;     // k-slice of this (compute|store) pair

  if (tid < 8) sFlag[tid] = 0;

  // XCD swizzle: 4096 blocks = 8 * 512 (bijective); heads grouped per XCD.
  const int bid = ((blockIdx.x & 7) << 9) | (blockIdx.x >> 3);
  const int bh = bid >> 6;     // 0..63
  const int qt = bid & 63;     // 32-row Q tile
  const int b  = bh >> 4;

  const float* Qh = Q + ((size_t)bh * S_ + (size_t)qt * 32) * D_;
  const float* Kh = K + (size_t)bh * S_ * D_;
  const float* Vh = V + (size_t)bh * S_ * D_;
  const int*   Mb = M + (size_t)b * S_;
  float* Ph = outP + (size_t)bh * S_ * S_ + (size_t)qt * 32 * S_;
  float* Oh = outO + ((size_t)bh * S_ + (size_t)qt * 32) * D_;

  volatile int* vFlag = sFlag;

  bf16x8 qa[2][2];
  f32x4 oacc[2][4];

  // ---------- pass 1 (compute waves): swapped QK^T row exp-sums, loads only ----------
  if (wid < 4) {
#pragma unroll
    for (int rt = 0; rt < 2; ++rt)
#pragma unroll
      for (int sk = 0; sk < 2; ++sk) {
        if (PRE)
          qa[rt][sk] = __builtin_bit_cast(bf16x8,
            *(const us8*)&Qb[((size_t)(bh * S_ + qt*32 + rt*16 + l15)) * D_ + sk*32 + l4*8]);
        else
          qa[rt][sk] = cvt8(Qh + (rt*16 + l15) * D_ + sk*32 + l4*8);
      }
    float rs[2] = {0.f, 0.f};
    for (int i = 0; i < 32; ++i) {
      const int col0 = kbase + i*16;
      const i32x4 mk4 = *(const i32x4*)&Mb[col0 + l4*4];
      bf16x8 kf0, kf1;
      if (PRE) {
        const unsigned short* kp = &Kb[(size_t)(bh * S_ + col0 + l15) * D_ + l4*8];
        kf0 = __builtin_bit_cast(bf16x8, *(const us8*)kp);
        kf1 = __builtin_bit_cast(bf16x8, *(const us8*)(kp + 32));
      } else {
        const float* kp = Kh + (size_t)(col0 + l15) * D_ + l4*8;
        kf0 = cvt8(kp); kf1 = cvt8(kp + 32);
      }
#pragma unroll
      for (int rt = 0; rt < 2; ++rt) {
        f32x4 acc = {0.f,0.f,0.f,0.f};
        acc = __builtin_amdgcn_mfma_f32_16x16x32_bf16(kf0, qa[rt][0], acc, 0,0,0);
        acc = __builtin_amdgcn_mfma_f32_16x16x32_bf16(kf1, qa[rt][1], acc, 0,0,0);
#pragma unroll
        for (int r = 0; r < 4; ++r)
          rs[rt] += mk4[r] ? __expf(acc[r] * 0.125f) : 0.f;
      }
    }
#pragma unroll
    for (int rt = 0; rt < 2; ++rt) {
      rs[rt] += __shfl_xor(rs[rt], 16);
      rs[rt] += __shfl_xor(rs[rt], 32);
    }
    if (l4 == 0) {
      sRed[cw][l15]      = rs[0];
      sRed[cw][16 + l15] = rs[1];
    }
  }
  __syncthreads();
  if (tid < 32) {
    float t = sRed[0][tid] + sRed[1][tid] + sRed[2][tid] + sRed[3][tid];
    sSum[tid] = 1.0f / t;
  }
  __syncthreads();

  // ---------- pass 2 ----------
  if (wid < 4) {
    // COMPUTE wave: recompute swapped QK^T per 64-col group -> exp bf16 stash -> PV.
#pragma unroll
    for (int rt = 0; rt < 2; ++rt)
#pragma unroll
      for (int dt = 0; dt < 4; ++dt)
        oacc[rt][dt] = (f32x4){0.f,0.f,0.f,0.f};

#pragma unroll 1
    for (int g = 0; g < 8; ++g) {
      const int c0 = kbase + g*64;
      if (g >= 2) {   // buffer g&1 must be consumed (group g-2 done)
        while (vFlag[4 + cw] < g - 1) __builtin_amdgcn_s_sleep(2);
        asm volatile("" ::: "memory");
      }
      unsigned short (&buf)[32][80] = sP[cw][g & 1];
#pragma unroll
      for (int ct = 0; ct < 4; ++ct) {
        const int col0 = c0 + ct*16;
        const i32x4 mk4 = *(const i32x4*)&Mb[col0 + l4*4];
        bf16x8 kf0, kf1;
        if (PRE) {
          const unsigned short* kp = &Kb[(size_t)(bh * S_ + col0 + l15) * D_ + l4*8];
          kf0 = __builtin_bit_cast(bf16x8, *(const us8*)kp);
          kf1 = __builtin_bit_cast(bf16x8, *(const us8*)(kp + 32));
        } else {
          const float* kp = Kh + (size_t)(col0 + l15) * D_ + l4*8;
          kf0 = cvt8(kp); kf1 = cvt8(kp + 32);
        }
#pragma unroll
        for (int rt = 0; rt < 2; ++rt) {
          f32x4 a = {0.f,0.f,0.f,0.f};
          a = __builtin_amdgcn_mfma_f32_16x16x32_bf16(kf0, qa[rt][0], a, 0,0,0);
          a = __builtin_amdgcn_mfma_f32_16x16x32_bf16(kf1, qa[rt][1], a, 0,0,0);
          // lane holds S[k=col0+l4*4+r][q=rt*16+l15]
          us4 pb;
#pragma unroll
          for (int r = 0; r < 4; ++r) {
            float e = mk4[r] ? __expf(a[r] * 0.125f) : 0.f;
            pb[r] = f2bf(e);
          }
          *(us4*)&buf[rt*16 + l15][ct*16 + l4*4] = pb;   // un-normalized exp
        }
      }
      asm volatile("s_waitcnt lgkmcnt(0)" ::: "memory");
      if (lane == 0) vFlag[cw] = g + 1;                   // publish group g
      // PV on the stash (un-normalized; rv deferred to epilogue)
#pragma unroll
      for (int kb = 0; kb < 2; ++kb) {
        bf16x8 pa[2];
#pragma unroll
        for (int rt = 0; rt < 2; ++rt)
          pa[rt] = __builtin_bit_cast(bf16x8,
            *(const us8*)&buf[rt*16 + l15][kb*32 + l4*8]);
#pragma unroll
        for (int dt = 0; dt < 4; ++dt) {
          us8 vb;
          if (PRE) {
            vb = *(const us8*)&Vt[((size_t)(bh * D_ + dt*16 + l15)) * S_ + c0 + kb*32 + l4*8];
          } else {
#pragma unroll
            for (int j = 0; j < 8; ++j)
              vb[j] = f2bf(Vh[(size_t)(c0 + kb*32 + l4*8 + j) * D_ + dt*16 + l15]);
          }
#pragma unroll
          for (int rt = 0; rt < 2; ++rt)
            oacc[rt][dt] = __builtin_amdgcn_mfma_f32_16x16x32_bf16(
                               pa[rt], __builtin_bit_cast(bf16x8, vb), oacc[rt][dt], 0,0,0);
        }
      }
    }
  } else {
    // STORE wave: no loads, no vmcnt waits. Drain stash -> scaled fp32 P stores.
    const int r4 = l4;           // 0..3
    const int q  = l15;          // col quad within 64-col group
    float rvs[8];
#pragma unroll
    for (int j = 0; j < 8; ++j) rvs[j] = sSum[j*4 + r4];
#pragma unroll 1
    for (int g = 0; g < 8; ++g) {
      while (vFlag[cw] < g + 1) __builtin_amdgcn_s_sleep(2);
      asm volatile("" ::: "memory");
      const unsigned short (&buf)[32][80] = sP[cw][g & 1];
      const int c0 = kbase + g*64;
      us4 e[8];
#pragma unroll
      for (int j = 0; j < 8; ++j)
        e[j] = *(const us4*)&buf[j*4 + r4][q*4];
      asm volatile("s_waitcnt lgkmcnt(0)" ::: "memory");
      if (lane == 0) vFlag[4 + cw] = g + 1;              // buffer free
#pragma unroll
      for (int j = 0; j < 8; ++j) {
        f32x4 w;
#pragma unroll
        for (int x = 0; x < 4; ++x) w[x] = bf2f(e[j][x]) * rvs[j];
        *(f32x4*)&Ph[(size_t)(j*4 + r4) * S_ + c0 + q*4] = w;   // 256B/row segments
      }
    }
  }

  // ---------- epilogue: cross-wave O reduction + deferred normalization ----------
  __syncthreads();                  // store waves done reading stash; drains P stores once
  if (wid < 4) {
    float* sO = (float*)&sP[cw][0][0][0];   // 32x64 f32 (8 KB) inside own 10.25 KB region
#pragma unroll
    for (int rt = 0; rt < 2; ++rt)
#pragma unroll
      for (int dt = 0; dt < 4; ++dt)
#pragma unroll
        for (int r = 0; r < 4; ++r)
          sO[(rt*16 + l4*4 + r)*64 + dt*16 + l15] = oacc[rt][dt][r];
  }
  __syncthreads();
  {
    const int row = tid >> 4;           // 0..31
    const int d0  = (tid & 15) * 4;
    f32x4 s = {0.f,0.f,0.f,0.f};
#pragma unroll
    for (int w = 0; w < 4; ++w)
      s += *(const f32x4*)((const float*)&sP[w][0][0][0] + row*64 + d0);
    const float rv = sSum[row];
    s[0]*=rv; s[1]*=rv; s[2]*=rv; s[3]*=rv;
    *(f32x4*)&Oh[(size_t)row * D_ + d0] = s;
  }
}

extern "C" void kernel_launch(void* const* d_in, const int* in_sizes, int n_in,
                              void* d_out, int out_size, void* d_ws, size_t ws_size,
                              hipStream_t stream) {
  const float* Q = (const float*)d_in[0];
  const float* K = (const float*)d_in[1];
  const float* V = (const float*)d_in[2];
  const int*   M = (const int*)d_in[3];
  float* outO = (float*)d_out;                                  // (B,H,S,D)
  float* outP = (float*)d_out + (size_t)4 * 16 * 2048 * 64;     // (B,H,S,S)

  const size_t bytesEach = (size_t)64 * 2048 * 64 * 2;          // 16 MiB per bf16 array
  const size_t need = 3 * bytesEach;

  if (ws_size >= need) {
    unsigned short* Vt = (unsigned short*)d_ws;
    unsigned short* Kb = (unsigned short*)((char*)d_ws + bytesEach);
    unsigned short* Qb = (unsigned short*)((char*)d_ws + 2 * bytesEach);
    const int n4 = 64 * 2048 * 64 / 4;
    cvt_bf16_kernel<<<dim3(2048), dim3(256), 0, stream>>>(K, Kb, n4);
    cvt_bf16_kernel<<<dim3(2048), dim3(256), 0, stream>>>(Q, Qb, n4);
    vtrans_kernel<<<dim3(2048), dim3(256), 0, stream>>>(V, Vt);
    attn_kernel<1><<<dim3(4096), dim3(512), 0, stream>>>(Q, K, V, M, Qb, Kb, Vt, outO, outP);
  } else {
    attn_kernel<0><<<dim3(4096), dim3(512), 0, stream>>>(Q, K, V, M,
        (const unsigned short*)nullptr, (const unsigned short*)nullptr,
        (const unsigned short*)nullptr, outO, outP);
  }
}

// Round 9
// 444.333 us; speedup vs baseline: 1.5437x; 1.3592x over previous
//
#include <hip/hip_runtime.h>
#include <cstdint>
#include <cstddef>

#define S_ 2048
#define D_ 64

typedef __attribute__((ext_vector_type(4))) float f32x4;
typedef __attribute__((ext_vector_type(4))) int i32x4;
typedef __attribute__((ext_vector_type(8))) __bf16 bf16x8;
typedef __attribute__((ext_vector_type(8))) unsigned short us8;
typedef __attribute__((ext_vector_type(4))) unsigned short us4;

static __device__ __forceinline__ unsigned short f2bf(float f) {
  unsigned int u = __builtin_bit_cast(unsigned int, f);
  u += 0x7fffu + ((u >> 16) & 1u);          // RNE (no NaNs in this problem)
  return (unsigned short)(u >> 16);
}
static __device__ __forceinline__ float bf2f(unsigned short h) {
  unsigned int u = ((unsigned int)h) << 16;
  return __builtin_bit_cast(float, u);
}
static __device__ __forceinline__ bf16x8 cvt8(const float* p) {
  f32x4 a = *(const f32x4*)p;
  f32x4 b = *(const f32x4*)(p + 4);
  us8 t;
  t[0]=f2bf(a[0]); t[1]=f2bf(a[1]); t[2]=f2bf(a[2]); t[3]=f2bf(a[3]);
  t[4]=f2bf(b[0]); t[5]=f2bf(b[1]); t[6]=f2bf(b[2]); t[7]=f2bf(b[3]);
  return __builtin_bit_cast(bf16x8, t);
}

// ---------- prekernel 1: f32 -> bf16 elementwise (Q, K) ----------
__global__ __launch_bounds__(256)
void cvt_bf16_kernel(const float* __restrict__ src, unsigned short* __restrict__ dst, int n4) {
  int i = blockIdx.x * 256 + threadIdx.x;
  int stride = gridDim.x * 256;
  for (; i < n4; i += stride) {
    f32x4 v = ((const f32x4*)src)[i];
    us4 o; o[0]=f2bf(v[0]); o[1]=f2bf(v[1]); o[2]=f2bf(v[2]); o[3]=f2bf(v[3]);
    ((us4*)dst)[i] = o;
  }
}

// ---------- prekernel 2: V [bh][s][d] f32 -> Vt [bh][d][s] bf16 ----------
__global__ __launch_bounds__(256)
void vtrans_kernel(const float* __restrict__ V, unsigned short* __restrict__ Vt) {
  __shared__ unsigned short T[64][72];
  const int bh = blockIdx.x >> 5;
  const int s0 = (blockIdx.x & 31) * 64;
  const int tid = threadIdx.x;
#pragma unroll
  for (int it = 0; it < 4; ++it) {
    int idx = it * 256 + tid;
    int s = idx >> 4, d4 = (idx & 15) * 4;
    f32x4 v = *(const f32x4*)&V[((size_t)bh * S_ + s0 + s) * D_ + d4];
    T[s][d4+0] = f2bf(v[0]); T[s][d4+1] = f2bf(v[1]);
    T[s][d4+2] = f2bf(v[2]); T[s][d4+3] = f2bf(v[3]);
  }
  __syncthreads();
#pragma unroll
  for (int it = 0; it < 2; ++it) {
    int idx = it * 256 + tid;
    int d = idx >> 3, s8 = (idx & 7) * 8;
    us8 w;
#pragma unroll
    for (int j = 0; j < 8; ++j) w[j] = T[s8 + j][d];
    *(us8*)&Vt[((size_t)bh * D_ + d) * S_ + s0 + s8] = w;
  }
}

// ---------- main fused attention: v5 structure + NON-TEMPORAL P/O stores ----------
template<int PRE>
__global__ __launch_bounds__(256, 4)
void attn_kernel(const float* __restrict__ Q, const float* __restrict__ K,
                 const float* __restrict__ V, const int* __restrict__ M,
                 const unsigned short* __restrict__ Qb,
                 const unsigned short* __restrict__ Kb,
                 const unsigned short* __restrict__ Vt,
                 float* __restrict__ outO, float* __restrict__ outP)
{
  // wave-private P stash [wave][32 q][64 k] bf16 (16 KB); aliased as f32 O-reduce
  // scratch [wave][16 q][64 d] (16 KB) in the epilogue.
  __shared__ __align__(16) unsigned short sP[4][32][64];
  __shared__ float sRed[4][32];
  __shared__ float sSum[32];

  const int tid  = threadIdx.x;
  const int wid  = tid >> 6;      // 0..3, owns k-slice [wid*512, wid*512+512)
  const int lane = tid & 63;
  const int l15  = lane & 15;
  const int l4   = lane >> 4;
  const int kbase = wid * 512;

  // XCD swizzle: 4096 blocks = 8 * 512 (bijective); heads grouped per XCD.
  const int bid = ((blockIdx.x & 7) << 9) | (blockIdx.x >> 3);
  const int bh = bid >> 6;     // 0..63
  const int qt = bid & 63;     // 32-row Q tile
  const int b  = bh >> 4;

  const float* Qh = Q + ((size_t)bh * S_ + (size_t)qt * 32) * D_;
  const float* Kh = K + (size_t)bh * S_ * D_;
  const float* Vh = V + (size_t)bh * S_ * D_;
  const int*   Mb = M + (size_t)b * S_;
  float* Ph = outP + (size_t)bh * S_ * S_ + (size_t)qt * 32 * S_;
  float* Oh = outO + ((size_t)bh * S_ + (size_t)qt * 32) * D_;

  // Q fragments: 32 rows (2 row-tiles) x K-depth 64
  bf16x8 qa[2][2];
#pragma unroll
  for (int rt = 0; rt < 2; ++rt)
#pragma unroll
    for (int sk = 0; sk < 2; ++sk) {
      if (PRE)
        qa[rt][sk] = __builtin_bit_cast(bf16x8,
          *(const us8*)&Qb[((size_t)(bh * S_ + qt*32 + rt*16 + l15)) * D_ + sk*32 + l4*8]);
      else
        qa[rt][sk] = cvt8(Qh + (rt*16 + l15) * D_ + sk*32 + l4*8);
    }

  // ---------- pass 1: row exp-sums over this wave's 512 cols ----------
  float rs[2][4] = {{0.f,0.f,0.f,0.f},{0.f,0.f,0.f,0.f}};
  for (int i = 0; i < 32; ++i) {
    const int col = kbase + i*16 + l15;
    const int mk = Mb[col];
    bf16x8 kf0, kf1;
    if (PRE) {
      const unsigned short* kp = &Kb[(size_t)(bh * S_ + col) * D_ + l4*8];
      kf0 = __builtin_bit_cast(bf16x8, *(const us8*)kp);
      kf1 = __builtin_bit_cast(bf16x8, *(const us8*)(kp + 32));
    } else {
      const float* kp = Kh + (size_t)col * D_ + l4*8;
      kf0 = cvt8(kp); kf1 = cvt8(kp + 32);
    }
#pragma unroll
    for (int rt = 0; rt < 2; ++rt) {
      f32x4 acc = {0.f,0.f,0.f,0.f};
      acc = __builtin_amdgcn_mfma_f32_16x16x32_bf16(qa[rt][0], kf0, acc, 0,0,0);
      acc = __builtin_amdgcn_mfma_f32_16x16x32_bf16(qa[rt][1], kf1, acc, 0,0,0);
#pragma unroll
      for (int r = 0; r < 4; ++r)
        rs[rt][r] += mk ? __expf(acc[r] * 0.125f) : 0.f;
    }
  }
#pragma unroll
  for (int rt = 0; rt < 2; ++rt)
#pragma unroll
    for (int r = 0; r < 4; ++r) {
#pragma unroll
      for (int o = 1; o < 16; o <<= 1)
        rs[rt][r] += __shfl_xor(rs[rt][r], o);
    }
  if (l15 == 0) {
#pragma unroll
    for (int rt = 0; rt < 2; ++rt)
#pragma unroll
      for (int r = 0; r < 4; ++r)
        sRed[wid][rt*16 + l4*4 + r] = rs[rt][r];
  }
  __syncthreads();
  if (tid < 32) {
    float t = sRed[0][tid] + sRed[1][tid] + sRed[2][tid] + sRed[3][tid];
    sSum[tid] = 1.0f / t;
  }
  __syncthreads();
  float rv[2][4];
#pragma unroll
  for (int rt = 0; rt < 2; ++rt)
#pragma unroll
    for (int r = 0; r < 4; ++r)
      rv[rt][r] = sSum[rt*16 + l4*4 + r];

  // ---------- pass 2: BARRIER-FREE. Per 64-col sub-slice: recompute, nt-store P,
  // stash wave-private, accumulate partial O over all 64 d ----------
  f32x4 oacc[2][4];
#pragma unroll
  for (int rt = 0; rt < 2; ++rt)
#pragma unroll
    for (int dt = 0; dt < 4; ++dt)
      oacc[rt][dt] = (f32x4){0.f,0.f,0.f,0.f};

  for (int it = 0; it < 8; ++it) {
    const int c0 = kbase + it*64;
    // QK^T + normalize + NON-TEMPORAL global store + LDS stash (wave-private)
#pragma unroll
    for (int ct = 0; ct < 4; ++ct) {
      const int col = c0 + ct*16 + l15;
      const int mk = Mb[col];
      bf16x8 kf0, kf1;
      if (PRE) {
        const unsigned short* kp = &Kb[(size_t)(bh * S_ + col) * D_ + l4*8];
        kf0 = __builtin_bit_cast(bf16x8, *(const us8*)kp);
        kf1 = __builtin_bit_cast(bf16x8, *(const us8*)(kp + 32));
      } else {
        const float* kp = Kh + (size_t)col * D_ + l4*8;
        kf0 = cvt8(kp); kf1 = cvt8(kp + 32);
      }
#pragma unroll
      for (int rt = 0; rt < 2; ++rt) {
        f32x4 a = {0.f,0.f,0.f,0.f};
        a = __builtin_amdgcn_mfma_f32_16x16x32_bf16(qa[rt][0], kf0, a, 0,0,0);
        a = __builtin_amdgcn_mfma_f32_16x16x32_bf16(qa[rt][1], kf1, a, 0,0,0);
#pragma unroll
        for (int r = 0; r < 4; ++r) {
          const int row = rt*16 + l4*4 + r;
          float p = mk ? __expf(a[r] * 0.125f) * rv[rt][r] : 0.f;
          __builtin_nontemporal_store(p, &Ph[(size_t)row * S_ + col]);
          sP[wid][row][(ct*16 + l15) ^ ((row & 7) << 3)] = f2bf(p);
        }
      }
    }
    // PV on this wave's own stash; partial O over all 64 d
#pragma unroll
    for (int kb = 0; kb < 2; ++kb) {
      bf16x8 pa[2];
#pragma unroll
      for (int rt = 0; rt < 2; ++rt) {
        const int row = rt*16 + l15;
        pa[rt] = __builtin_bit_cast(bf16x8,
          *(const us8*)&sP[wid][row][(kb*32 + l4*8) ^ ((row & 7) << 3)]);
      }
#pragma unroll
      for (int dt = 0; dt < 4; ++dt) {
        us8 vb;
        if (PRE) {
          vb = *(const us8*)&Vt[((size_t)(bh * D_ + dt*16 + l15)) * S_ + c0 + kb*32 + l4*8];
        } else {
#pragma unroll
          for (int j = 0; j < 8; ++j)
            vb[j] = f2bf(Vh[(size_t)(c0 + kb*32 + l4*8 + j) * D_ + dt*16 + l15]);
        }
#pragma unroll
        for (int rt = 0; rt < 2; ++rt)
          oacc[rt][dt] = __builtin_amdgcn_mfma_f32_16x16x32_bf16(
                             pa[rt], __builtin_bit_cast(bf16x8, vb), oacc[rt][dt], 0,0,0);
      }
    }
  }

  // ---------- epilogue: cross-wave O reduction (2 chunks of 16 rows) ----------
  float* sO = (float*)&sP[0][0][0];   // [4][16][64] f32, aliases sP (16 KB)
#pragma unroll
  for (int rt = 0; rt < 2; ++rt) {
    __syncthreads();   // stash reads done / previous chunk reads done
#pragma unroll
    for (int dt = 0; dt < 4; ++dt)
#pragma unroll
      for (int r = 0; r < 4; ++r)
        sO[wid*1024 + (l4*4 + r)*64 + dt*16 + l15] = oacc[rt][dt][r];
    __syncthreads();
    {
      const int row = tid >> 4;
      const int d0 = (tid & 15) * 4;
      f32x4 s = *(const f32x4*)&sO[row*64 + d0];
      s += *(const f32x4*)&sO[1024 + row*64 + d0];
      s += *(const f32x4*)&sO[2048 + row*64 + d0];
      s += *(const f32x4*)&sO[3072 + row*64 + d0];
      __builtin_nontemporal_store(s, (f32x4*)&Oh[(size_t)(rt*16 + row) * D_ + d0]);
    }
  }
}

extern "C" void kernel_launch(void* const* d_in, const int* in_sizes, int n_in,
                              void* d_out, int out_size, void* d_ws, size_t ws_size,
                              hipStream_t stream) {
  const float* Q = (const float*)d_in[0];
  const float* K = (const float*)d_in[1];
  const float* V = (const float*)d_in[2];
  const int*   M = (const int*)d_in[3];
  float* outO = (float*)d_out;                                  // (B,H,S,D)
  float* outP = (float*)d_out + (size_t)4 * 16 * 2048 * 64;     // (B,H,S,S)

  const size_t bytesEach = (size_t)64 * 2048 * 64 * 2;          // 16 MiB per bf16 array
  const size_t need = 3 * bytesEach;

  if (ws_size >= need) {
    unsigned short* Vt = (unsigned short*)d_ws;
    unsigned short* Kb = (unsigned short*)((char*)d_ws + bytesEach);
    unsigned short* Qb = (unsigned short*)((char*)d_ws + 2 * bytesEach);
    const int n4 = 64 * 2048 * 64 / 4;
    cvt_bf16_kernel<<<dim3(2048), dim3(256), 0, stream>>>(K, Kb, n4);
    cvt_bf16_kernel<<<dim3(2048), dim3(256), 0, stream>>>(Q, Qb, n4);
    vtrans_kernel<<<dim3(2048), dim3(256), 0, stream>>>(V, Vt);
    attn_kernel<1><<<dim3(4096), dim3(256), 0, stream>>>(Q, K, V, M, Qb, Kb, Vt, outO, outP);
  } else {
    attn_kernel<0><<<dim3(4096), dim3(256), 0, stream>>>(Q, K, V, M,
        (const unsigned short*)nullptr, (const unsigned short*)nullptr,
        (const unsigned short*)nullptr, outO, outP);
  }
}